// Round 3
// baseline (756.023 us; speedup 1.0000x reference)
//
#include <hip/hip_runtime.h>
#include <cstddef>

#define HWDIM 36
#define PIX   1296      // 36*36
#define PIX4  324       // PIX/4
#define CIN   64
#define CENC  8
#define HD    2
#define T_SEQ 16
#define PP    9
#define NPOS  81        // 9*9
#define FLATD 162       // 2*81
#define ODIM  24
#define BLOCK 384

__device__ __forceinline__ float sigm(float x) {
    return 1.f / (1.f + __expf(-x));
}
__device__ __forceinline__ float tanh_f(float x) {
    x = fminf(15.f, fmaxf(-15.f, x));
    float e = __expf(2.f * x);
    return (e - 1.f) / (e + 1.f);
}
__device__ __forceinline__ void fma4(float4& a, float w, const float4& v) {
    a.x = fmaf(w, v.x, a.x);
    a.y = fmaf(w, v.y, a.y);
    a.z = fmaf(w, v.z, a.z);
    a.w = fmaf(w, v.w, a.w);
}

__global__ __launch_bounds__(BLOCK) void lstm_pose_fused(
    const float* __restrict__ color, const float* __restrict__ geo,
    const float* __restrict__ enc_w1, const float* __restrict__ enc_b1,
    const float* __restrict__ enc_w2, const float* __restrict__ enc_b2,
    const float* __restrict__ lw1, const float* __restrict__ lb1,
    const float* __restrict__ lw2, const float* __restrict__ lb2,
    const float* __restrict__ ow, const float* __restrict__ ob,
    float* __restrict__ out)
{
    __shared__ __align__(16) float s_enc[CENC][PIX];     // 41.5 KB
    __shared__ __align__(16) float s_fw[CIN * CENC];     // fused W, layout [c][o]
    __shared__ float s_fb[CENC];
    __shared__ float s_w1[80], s_b1[8], s_w2[32], s_b2[8];
    __shared__ float s_flat[FLATD + 2];

    const int t = threadIdx.x;
    const int n = blockIdx.x;

    // ---- Phase 0: fuse encoder weights (W2@W1, W2@b1+b2), stage LSTM weights ----
    // Two 1x1 convs with no nonlinearity between them compose into one 64->8 map.
    for (int i = t; i < CIN * CENC; i += BLOCK) {
        const int c = i >> 3, o = i & 7;
        float s = 0.f;
        #pragma unroll
        for (int m = 0; m < 32; ++m)
            s = fmaf(enc_w2[o * 32 + m], enc_w1[m * 64 + c], s);
        s_fw[i] = s;   // s_fw[c*8+o]
    }
    if (t < 8) {
        float s = enc_b2[t];
        #pragma unroll
        for (int m = 0; m < 32; ++m)
            s = fmaf(enc_w2[t * 32 + m], enc_b1[m], s);
        s_fb[t] = s;
    }
    // spread small weight staging over different waves
    if (t >= 64  && t < 144) s_w1[t - 64]  = lw1[t - 64];
    if (t >= 160 && t < 168) s_b1[t - 160] = lb1[t - 160];
    if (t >= 192 && t < 224) s_w2[t - 192] = lw2[t - 192];
    if (t >= 256 && t < 264) s_b2[t - 256] = lb2[t - 256];
    __syncthreads();

    // ---- Phase 1: fused 64->8 encoder, streaming both inputs (HBM-bound) ----
    if (t < PIX4) {
        const float4* c4 = reinterpret_cast<const float4*>(color + (size_t)n * 32 * PIX);
        const float4* g4 = reinterpret_cast<const float4*>(geo   + (size_t)n * 32 * PIX);

        float4 acc[8];
        #pragma unroll
        for (int o = 0; o < 8; ++o) {
            const float b = s_fb[o];
            acc[o] = make_float4(b, b, b, b);
        }

        // 64 virtual channels: even -> color[c/2], odd -> geo[c/2]; interleaved
        // so independent loads from both streams are in flight together.
        #pragma unroll 8
        for (int cc = 0; cc < 64; ++cc) {
            const int c = cc >> 1;
            const float4 v = (cc & 1) ? g4[c * PIX4 + t] : c4[c * PIX4 + t];
            const int wbase = ((cc & 1) ? (c + 32) : c) * 8;
            const float4 wl = *reinterpret_cast<const float4*>(&s_fw[wbase]);
            const float4 wh = *reinterpret_cast<const float4*>(&s_fw[wbase + 4]);
            fma4(acc[0], wl.x, v); fma4(acc[1], wl.y, v);
            fma4(acc[2], wl.z, v); fma4(acc[3], wl.w, v);
            fma4(acc[4], wh.x, v); fma4(acc[5], wh.y, v);
            fma4(acc[6], wh.z, v); fma4(acc[7], wh.w, v);
        }
        #pragma unroll
        for (int o = 0; o < 8; ++o)
            *reinterpret_cast<float4*>(&s_enc[o][t * 4]) = acc[o];
    }
    __syncthreads();

    // ---- Phase 2: per-position double ConvLSTM chain (1x1 kernel => independent pixels) ----
    if (t < NPOS) {
        const int ph = t / PP, pw = t % PP;
        float h1[2] = {0.f, 0.f}, c1[2] = {0.f, 0.f};
        float h2[2] = {0.f, 0.f}, c2[2] = {0.f, 0.f};

        for (int step = 0; step < T_SEQ; ++step) {
            const int bh = step >> 2, bw = step & 3;
            const int pix = (bh * PP + ph) * HWDIM + (bw * PP + pw);

            float x[CENC];
            #pragma unroll
            for (int c = 0; c < CENC; ++c) x[c] = s_enc[c][pix];

            // layer 1: gates[j] = b1[j] + W1[j,0:8].x + W1[j,8:10].h1
            float g1[8];
            #pragma unroll
            for (int j = 0; j < 8; ++j) {
                float s = s_b1[j];
                #pragma unroll
                for (int c = 0; c < 8; ++c) s = fmaf(s_w1[j * 10 + c], x[c], s);
                s = fmaf(s_w1[j * 10 + 8], h1[0], s);
                s = fmaf(s_w1[j * 10 + 9], h1[1], s);
                g1[j] = s;
            }
            #pragma unroll
            for (int d = 0; d < 2; ++d) {
                const float i_ = sigm(g1[0 + d]);
                const float f_ = sigm(g1[2 + d]);
                const float o_ = sigm(g1[4 + d]);
                const float gg = tanh_f(g1[6 + d]);
                c1[d] = f_ * c1[d] + i_ * gg;
                h1[d] = o_ * tanh_f(c1[d]);
            }

            // layer 2: cat = [h1(2), h2(2)]
            float g2[8];
            #pragma unroll
            for (int j = 0; j < 8; ++j) {
                float s = s_b2[j];
                s = fmaf(s_w2[j * 4 + 0], h1[0], s);
                s = fmaf(s_w2[j * 4 + 1], h1[1], s);
                s = fmaf(s_w2[j * 4 + 2], h2[0], s);
                s = fmaf(s_w2[j * 4 + 3], h2[1], s);
                g2[j] = s;
            }
            #pragma unroll
            for (int d = 0; d < 2; ++d) {
                const float i_ = sigm(g2[0 + d]);
                const float f_ = sigm(g2[2 + d]);
                const float o_ = sigm(g2[4 + d]);
                const float gg = tanh_f(g2[6 + d]);
                c2[d] = f_ * c2[d] + i_ * gg;
                h2[d] = o_ * tanh_f(c2[d]);
            }
        }
        // last timestep of layer 2, flattened as [c*81 + pos]
        s_flat[0 * NPOS + t] = h2[0];
        s_flat[1 * NPOS + t] = h2[1];
    }
    __syncthreads();

    // ---- Phase 3: final linear [162] -> [24] ----
    if (t < ODIM) {
        float s = ob[t];
        const float* w = ow + t * FLATD;
        #pragma unroll 6
        for (int k = 0; k < FLATD; ++k) s = fmaf(w[k], s_flat[k], s);
        out[(size_t)n * ODIM + t] = s;
    }
}

extern "C" void kernel_launch(void* const* d_in, const int* in_sizes, int n_in,
                              void* d_out, int out_size, void* d_ws, size_t ws_size,
                              hipStream_t stream) {
    const float* color  = (const float*)d_in[0];
    const float* geo    = (const float*)d_in[1];
    const float* enc_w1 = (const float*)d_in[2];
    const float* enc_b1 = (const float*)d_in[3];
    const float* enc_w2 = (const float*)d_in[4];
    const float* enc_b2 = (const float*)d_in[5];
    const float* lw1    = (const float*)d_in[6];
    const float* lb1    = (const float*)d_in[7];
    const float* lw2    = (const float*)d_in[8];
    const float* lb2    = (const float*)d_in[9];
    const float* ow     = (const float*)d_in[10];
    const float* ob     = (const float*)d_in[11];
    float* out = (float*)d_out;

    const int nsamp = in_sizes[0] / (32 * PIX);   // 2048

    lstm_pose_fused<<<nsamp, BLOCK, 0, stream>>>(
        color, geo, enc_w1, enc_b1, enc_w2, enc_b2,
        lw1, lb1, lw2, lb2, ow, ob, out);
}

// Round 4
// 752.280 us; speedup vs baseline: 1.0050x; 1.0050x over previous
//
#include <hip/hip_runtime.h>
#include <cstddef>

#define HWDIM 36
#define PIX   1296      // 36*36
#define PIX4  324       // PIX/4
#define CIN   64
#define CENC  8
#define T_SEQ 16
#define PP    9
#define NPOS  81        // 9*9
#define FLATD 162       // 2*81
#define ODIM  24

__device__ __forceinline__ float sigm(float x) {
    return 1.f / (1.f + __expf(-x));
}
__device__ __forceinline__ float tanh_f(float x) {
    x = fminf(15.f, fmaxf(-15.f, x));
    float e = __expf(2.f * x);
    return (e - 1.f) / (e + 1.f);
}
__device__ __forceinline__ void fma4(float4& a, float w, const float4& v) {
    a.x = fmaf(w, v.x, a.x);
    a.y = fmaf(w, v.y, a.y);
    a.z = fmaf(w, v.z, a.z);
    a.w = fmaf(w, v.w, a.w);
}

// ---------------------------------------------------------------------------
// Kernel 1: fused 64->8 encoder as a pure streaming map.
// One thread per float4-pixel; no big LDS so many blocks co-reside per CU.
// ---------------------------------------------------------------------------
#define K1_BLOCK 256

__global__ __launch_bounds__(K1_BLOCK) void enc_stream(
    const float* __restrict__ color, const float* __restrict__ geo,
    const float* __restrict__ enc_w1, const float* __restrict__ enc_b1,
    const float* __restrict__ enc_w2, const float* __restrict__ enc_b2,
    float* __restrict__ enc_out, int total4)
{
    __shared__ __align__(16) float s_fw[CIN * CENC];   // fused W, layout [c][o]
    __shared__ float s_fb[CENC];

    const int t = threadIdx.x;

    // fuse the two 1x1 convs (no nonlinearity between them): W = W2@W1, b = W2@b1+b2
    for (int i = t; i < CIN * CENC; i += K1_BLOCK) {
        const int c = i >> 3, o = i & 7;
        float s = 0.f;
        #pragma unroll
        for (int m = 0; m < 32; ++m)
            s = fmaf(enc_w2[o * 32 + m], enc_w1[m * 64 + c], s);
        s_fw[i] = s;
    }
    if (t < CENC) {
        float s = enc_b2[t];
        #pragma unroll
        for (int m = 0; m < 32; ++m)
            s = fmaf(enc_w2[t * 32 + m], enc_b1[m], s);
        s_fb[t] = s;
    }
    __syncthreads();

    const int u = blockIdx.x * K1_BLOCK + t;
    if (u >= total4) return;
    const int n = u / PIX4;
    const int p = u - n * PIX4;

    const float4* c4 = reinterpret_cast<const float4*>(color + (size_t)n * 32 * PIX) + p;
    const float4* g4 = reinterpret_cast<const float4*>(geo   + (size_t)n * 32 * PIX) + p;

    float4 acc[8];
    #pragma unroll
    for (int o = 0; o < 8; ++o) {
        const float b = s_fb[o];
        acc[o] = make_float4(b, b, b, b);
    }

    #pragma unroll 8
    for (int cc = 0; cc < 64; ++cc) {
        const int c = cc >> 1;
        const float4 v = (cc & 1) ? g4[c * PIX4] : c4[c * PIX4];
        const int wbase = ((cc & 1) ? (c + 32) : c) * 8;
        const float4 wl = *reinterpret_cast<const float4*>(&s_fw[wbase]);
        const float4 wh = *reinterpret_cast<const float4*>(&s_fw[wbase + 4]);
        fma4(acc[0], wl.x, v); fma4(acc[1], wl.y, v);
        fma4(acc[2], wl.z, v); fma4(acc[3], wl.w, v);
        fma4(acc[4], wh.x, v); fma4(acc[5], wh.y, v);
        fma4(acc[6], wh.z, v); fma4(acc[7], wh.w, v);
    }

    float4* op = reinterpret_cast<float4*>(enc_out + (size_t)n * CENC * PIX);
    #pragma unroll
    for (int o = 0; o < 8; ++o)
        op[o * PIX4 + p] = acc[o];   // enc layout [n][c][pix], coalesced
}

// ---------------------------------------------------------------------------
// Kernel 2: one thread per (sample, position) LSTM chain; block = 4 samples.
// Final 162->24 linear reduced through tiny LDS.
// ---------------------------------------------------------------------------
#define K2_BLOCK 384

__global__ __launch_bounds__(K2_BLOCK) void lstm_head(
    const float* __restrict__ enc,
    const float* __restrict__ lw1, const float* __restrict__ lb1,
    const float* __restrict__ lw2, const float* __restrict__ lb2,
    const float* __restrict__ ow,  const float* __restrict__ ob,
    float* __restrict__ out, int nsamp)
{
    __shared__ float s_w1[80], s_b1[8], s_w2[32], s_b2[8];
    __shared__ float s_flat[4][FLATD];

    const int t = threadIdx.x;
    if (t < 80)       s_w1[t]       = lw1[t];
    else if (t < 88)  s_b1[t - 80]  = lb1[t - 80];
    else if (t < 120) s_w2[t - 88]  = lw2[t - 88];
    else if (t < 128) s_b2[t - 120] = lb2[t - 120];
    __syncthreads();

    if (t < 4 * NPOS) {
        const int s   = t / NPOS;
        const int pos = t - s * NPOS;
        const int n   = blockIdx.x * 4 + s;
        if (n < nsamp) {
            const int ph = pos / PP, pw = pos - ph * PP;
            const float* ep = enc + (size_t)n * CENC * PIX;

            float h1[2] = {0.f, 0.f}, c1[2] = {0.f, 0.f};
            float h2[2] = {0.f, 0.f}, c2[2] = {0.f, 0.f};

            for (int step = 0; step < T_SEQ; ++step) {
                const int bh = step >> 2, bw = step & 3;
                const int pix = (bh * PP + ph) * HWDIM + (bw * PP + pw);

                float x[CENC];
                #pragma unroll
                for (int c = 0; c < CENC; ++c) x[c] = ep[c * PIX + pix];

                float g1[8];
                #pragma unroll
                for (int j = 0; j < 8; ++j) {
                    float s_ = s_b1[j];
                    #pragma unroll
                    for (int c = 0; c < 8; ++c) s_ = fmaf(s_w1[j * 10 + c], x[c], s_);
                    s_ = fmaf(s_w1[j * 10 + 8], h1[0], s_);
                    s_ = fmaf(s_w1[j * 10 + 9], h1[1], s_);
                    g1[j] = s_;
                }
                #pragma unroll
                for (int d = 0; d < 2; ++d) {
                    const float i_ = sigm(g1[0 + d]);
                    const float f_ = sigm(g1[2 + d]);
                    const float o_ = sigm(g1[4 + d]);
                    const float gg = tanh_f(g1[6 + d]);
                    c1[d] = f_ * c1[d] + i_ * gg;
                    h1[d] = o_ * tanh_f(c1[d]);
                }

                float g2[8];
                #pragma unroll
                for (int j = 0; j < 8; ++j) {
                    float s_ = s_b2[j];
                    s_ = fmaf(s_w2[j * 4 + 0], h1[0], s_);
                    s_ = fmaf(s_w2[j * 4 + 1], h1[1], s_);
                    s_ = fmaf(s_w2[j * 4 + 2], h2[0], s_);
                    s_ = fmaf(s_w2[j * 4 + 3], h2[1], s_);
                    g2[j] = s_;
                }
                #pragma unroll
                for (int d = 0; d < 2; ++d) {
                    const float i_ = sigm(g2[0 + d]);
                    const float f_ = sigm(g2[2 + d]);
                    const float o_ = sigm(g2[4 + d]);
                    const float gg = tanh_f(g2[6 + d]);
                    c2[d] = f_ * c2[d] + i_ * gg;
                    h2[d] = o_ * tanh_f(c2[d]);
                }
            }
            s_flat[s][pos]        = h2[0];
            s_flat[s][NPOS + pos] = h2[1];
        }
    }
    __syncthreads();

    if (t < 4 * ODIM) {
        const int s = t / ODIM, o = t - s * ODIM;
        const int n = blockIdx.x * 4 + s;
        if (n < nsamp) {
            float sum = ob[o];
            const float* w = ow + o * FLATD;
            #pragma unroll 6
            for (int k = 0; k < FLATD; ++k) sum = fmaf(w[k], s_flat[s][k], sum);
            out[(size_t)n * ODIM + o] = sum;
        }
    }
}

// ---------------------------------------------------------------------------
// Fallback: original fused single kernel (used only if d_ws is too small).
// ---------------------------------------------------------------------------
#define BLOCK 384

__global__ __launch_bounds__(BLOCK) void lstm_pose_fused(
    const float* __restrict__ color, const float* __restrict__ geo,
    const float* __restrict__ enc_w1, const float* __restrict__ enc_b1,
    const float* __restrict__ enc_w2, const float* __restrict__ enc_b2,
    const float* __restrict__ lw1, const float* __restrict__ lb1,
    const float* __restrict__ lw2, const float* __restrict__ lb2,
    const float* __restrict__ ow, const float* __restrict__ ob,
    float* __restrict__ out)
{
    __shared__ __align__(16) float s_enc[CENC][PIX];
    __shared__ __align__(16) float s_fw[CIN * CENC];
    __shared__ float s_fb[CENC];
    __shared__ float s_w1[80], s_b1[8], s_w2[32], s_b2[8];
    __shared__ float s_flat[FLATD + 2];

    const int t = threadIdx.x;
    const int n = blockIdx.x;

    for (int i = t; i < CIN * CENC; i += BLOCK) {
        const int c = i >> 3, o = i & 7;
        float s = 0.f;
        #pragma unroll
        for (int m = 0; m < 32; ++m)
            s = fmaf(enc_w2[o * 32 + m], enc_w1[m * 64 + c], s);
        s_fw[i] = s;
    }
    if (t < 8) {
        float s = enc_b2[t];
        #pragma unroll
        for (int m = 0; m < 32; ++m)
            s = fmaf(enc_w2[t * 32 + m], enc_b1[m], s);
        s_fb[t] = s;
    }
    if (t >= 64  && t < 144) s_w1[t - 64]  = lw1[t - 64];
    if (t >= 160 && t < 168) s_b1[t - 160] = lb1[t - 160];
    if (t >= 192 && t < 224) s_w2[t - 192] = lw2[t - 192];
    if (t >= 256 && t < 264) s_b2[t - 256] = lb2[t - 256];
    __syncthreads();

    if (t < PIX4) {
        const float4* c4 = reinterpret_cast<const float4*>(color + (size_t)n * 32 * PIX);
        const float4* g4 = reinterpret_cast<const float4*>(geo   + (size_t)n * 32 * PIX);
        float4 acc[8];
        #pragma unroll
        for (int o = 0; o < 8; ++o) {
            const float b = s_fb[o];
            acc[o] = make_float4(b, b, b, b);
        }
        #pragma unroll 8
        for (int cc = 0; cc < 64; ++cc) {
            const int c = cc >> 1;
            const float4 v = (cc & 1) ? g4[c * PIX4 + t] : c4[c * PIX4 + t];
            const int wbase = ((cc & 1) ? (c + 32) : c) * 8;
            const float4 wl = *reinterpret_cast<const float4*>(&s_fw[wbase]);
            const float4 wh = *reinterpret_cast<const float4*>(&s_fw[wbase + 4]);
            fma4(acc[0], wl.x, v); fma4(acc[1], wl.y, v);
            fma4(acc[2], wl.z, v); fma4(acc[3], wl.w, v);
            fma4(acc[4], wh.x, v); fma4(acc[5], wh.y, v);
            fma4(acc[6], wh.z, v); fma4(acc[7], wh.w, v);
        }
        #pragma unroll
        for (int o = 0; o < 8; ++o)
            *reinterpret_cast<float4*>(&s_enc[o][t * 4]) = acc[o];
    }
    __syncthreads();

    if (t < NPOS) {
        const int ph = t / PP, pw = t % PP;
        float h1[2] = {0.f, 0.f}, c1[2] = {0.f, 0.f};
        float h2[2] = {0.f, 0.f}, c2[2] = {0.f, 0.f};
        for (int step = 0; step < T_SEQ; ++step) {
            const int bh = step >> 2, bw = step & 3;
            const int pix = (bh * PP + ph) * HWDIM + (bw * PP + pw);
            float x[CENC];
            #pragma unroll
            for (int c = 0; c < CENC; ++c) x[c] = s_enc[c][pix];
            float g1[8];
            #pragma unroll
            for (int j = 0; j < 8; ++j) {
                float s = s_b1[j];
                #pragma unroll
                for (int c = 0; c < 8; ++c) s = fmaf(s_w1[j * 10 + c], x[c], s);
                s = fmaf(s_w1[j * 10 + 8], h1[0], s);
                s = fmaf(s_w1[j * 10 + 9], h1[1], s);
                g1[j] = s;
            }
            #pragma unroll
            for (int d = 0; d < 2; ++d) {
                const float i_ = sigm(g1[0 + d]);
                const float f_ = sigm(g1[2 + d]);
                const float o_ = sigm(g1[4 + d]);
                const float gg = tanh_f(g1[6 + d]);
                c1[d] = f_ * c1[d] + i_ * gg;
                h1[d] = o_ * tanh_f(c1[d]);
            }
            float g2[8];
            #pragma unroll
            for (int j = 0; j < 8; ++j) {
                float s = s_b2[j];
                s = fmaf(s_w2[j * 4 + 0], h1[0], s);
                s = fmaf(s_w2[j * 4 + 1], h1[1], s);
                s = fmaf(s_w2[j * 4 + 2], h2[0], s);
                s = fmaf(s_w2[j * 4 + 3], h2[1], s);
                g2[j] = s;
            }
            #pragma unroll
            for (int d = 0; d < 2; ++d) {
                const float i_ = sigm(g2[0 + d]);
                const float f_ = sigm(g2[2 + d]);
                const float o_ = sigm(g2[4 + d]);
                const float gg = tanh_f(g2[6 + d]);
                c2[d] = f_ * c2[d] + i_ * gg;
                h2[d] = o_ * tanh_f(c2[d]);
            }
        }
        s_flat[0 * NPOS + t] = h2[0];
        s_flat[1 * NPOS + t] = h2[1];
    }
    __syncthreads();

    if (t < ODIM) {
        float s = ob[t];
        const float* w = ow + t * FLATD;
        #pragma unroll 6
        for (int k = 0; k < FLATD; ++k) s = fmaf(w[k], s_flat[k], s);
        out[(size_t)n * ODIM + t] = s;
    }
}

extern "C" void kernel_launch(void* const* d_in, const int* in_sizes, int n_in,
                              void* d_out, int out_size, void* d_ws, size_t ws_size,
                              hipStream_t stream) {
    const float* color  = (const float*)d_in[0];
    const float* geo    = (const float*)d_in[1];
    const float* enc_w1 = (const float*)d_in[2];
    const float* enc_b1 = (const float*)d_in[3];
    const float* enc_w2 = (const float*)d_in[4];
    const float* enc_b2 = (const float*)d_in[5];
    const float* lw1    = (const float*)d_in[6];
    const float* lb1    = (const float*)d_in[7];
    const float* lw2    = (const float*)d_in[8];
    const float* lb2    = (const float*)d_in[9];
    const float* ow     = (const float*)d_in[10];
    const float* ob     = (const float*)d_in[11];
    float* out = (float*)d_out;

    const int nsamp = in_sizes[0] / (32 * PIX);   // 2048
    const size_t enc_bytes = (size_t)nsamp * CENC * PIX * sizeof(float);  // ~81 MB

    if (ws_size >= enc_bytes) {
        float* enc = (float*)d_ws;
        const int total4 = nsamp * PIX4;
        const int g1 = (total4 + K1_BLOCK - 1) / K1_BLOCK;
        enc_stream<<<g1, K1_BLOCK, 0, stream>>>(
            color, geo, enc_w1, enc_b1, enc_w2, enc_b2, enc, total4);
        const int g2 = (nsamp + 3) / 4;
        lstm_head<<<g2, K2_BLOCK, 0, stream>>>(
            enc, lw1, lb1, lw2, lb2, ow, ob, out, nsamp);
    } else {
        lstm_pose_fused<<<nsamp, BLOCK, 0, stream>>>(
            color, geo, enc_w1, enc_b1, enc_w2, enc_b2,
            lw1, lb1, lw2, lb2, ow, ob, out);
    }
}